// Round 3
// baseline (402.304 us; speedup 1.0000x reference)
//
#include <hip/hip_runtime.h>

#define N_NODES 50000
#define N_EDGES 625000
#define FEAT 128
#define NEG_SLOPE 0.2f
#define BM 32
#define NB_SCAN 196   // ceil(50000/256)

// ---------------- CSR build ----------------

__global__ __launch_bounds__(256) void hist_kernel(const int* __restrict__ dst,
                                                   int* __restrict__ cnt) {
  int e = blockIdx.x * 256 + threadIdx.x;
  if (e < N_EDGES) atomicAdd(&cnt[dst[e]], 1);
}

__global__ __launch_bounds__(256) void scan_part_kernel(const int* __restrict__ cnt,
                                                        int* __restrict__ part) {
  __shared__ int s[256];
  int i = blockIdx.x * 256 + threadIdx.x;
  s[threadIdx.x] = (i < N_NODES) ? cnt[i] : 0;
  __syncthreads();
  for (int o = 128; o > 0; o >>= 1) {
    if (threadIdx.x < o) s[threadIdx.x] += s[threadIdx.x + o];
    __syncthreads();
  }
  if (threadIdx.x == 0) part[blockIdx.x] = s[0];
}

__global__ __launch_bounds__(256) void scan_top_kernel(int* __restrict__ part,
                                                       int* __restrict__ offs) {
  __shared__ int s[256];
  int tid = threadIdx.x;
  int v = (tid < NB_SCAN) ? part[tid] : 0;
  s[tid] = v;
  __syncthreads();
  for (int o = 1; o < 256; o <<= 1) {
    int t = (tid >= o) ? s[tid - o] : 0;
    __syncthreads();
    s[tid] += t;
    __syncthreads();
  }
  if (tid < NB_SCAN) part[tid] = s[tid] - v;  // exclusive scan of block sums
  if (tid == 255) offs[N_NODES] = s[255];     // total (= N_EDGES)
}

__global__ __launch_bounds__(256) void scan_down_kernel(int* __restrict__ cnt,
                                                        const int* __restrict__ part,
                                                        int* __restrict__ offs) {
  __shared__ int s[256];
  int tid = threadIdx.x;
  int i = blockIdx.x * 256 + tid;
  int v = (i < N_NODES) ? cnt[i] : 0;
  s[tid] = v;
  __syncthreads();
  for (int o = 1; o < 256; o <<= 1) {
    int t = (tid >= o) ? s[tid - o] : 0;
    __syncthreads();
    s[tid] += t;
    __syncthreads();
  }
  if (i < N_NODES) {
    int excl = s[tid] - v + part[blockIdx.x];
    offs[i] = excl;
    cnt[i] = excl;  // becomes the fill cursor
  }
}

__global__ __launch_bounds__(256) void fill_kernel(const int* __restrict__ src,
                                                   const int* __restrict__ dst,
                                                   int* __restrict__ cursor,
                                                   int* __restrict__ ssrc) {
  int e = blockIdx.x * 256 + threadIdx.x;
  if (e < N_EDGES) {
    int pos = atomicAdd(&cursor[dst[e]], 1);
    ssrc[pos] = src[e];
  }
}

// ---------------- GEMM: h = act(in) @ W, fused el = h@al, er = h@ar ----------------
// block: 256 threads = 8 row-groups x 32 col-groups; 4x4 outputs per thread.

__global__ __launch_bounds__(256) void gemm_kernel(
    const float* __restrict__ in, const float* __restrict__ W,
    const float* __restrict__ al, const float* __restrict__ ar,
    float* __restrict__ h, float* __restrict__ el, float* __restrict__ er,
    int applyRelu)
{
  __shared__ float A[BM][FEAT];    // 16 KB, full K staged once
  __shared__ float Wl[32][FEAT];   // 16 KB, K-chunked
  const int tid = threadIdx.x;
  const int row0 = blockIdx.x * BM;

  // stage A tile (apply input relu for layers 2,3)
#pragma unroll
  for (int it = 0; it < 4; ++it) {
    int f = it * 256 + tid;        // float4 id within 32x128 tile
    int r = f >> 5, c4 = f & 31;
    int gr = row0 + r;
    float4 v = make_float4(0.f, 0.f, 0.f, 0.f);
    if (gr < N_NODES) {
      v = *(const float4*)(in + (size_t)gr * FEAT + c4 * 4);
      if (applyRelu) {
        v.x = fmaxf(v.x, 0.f); v.y = fmaxf(v.y, 0.f);
        v.z = fmaxf(v.z, 0.f); v.w = fmaxf(v.w, 0.f);
      }
    }
    *(float4*)(&A[r][c4 * 4]) = v;
  }

  const int cg = tid & 31, rg = tid >> 5;
  const int c0 = cg * 4, r0 = rg * 4;
  float acc[4][4];
#pragma unroll
  for (int i = 0; i < 4; ++i) { acc[i][0] = 0.f; acc[i][1] = 0.f; acc[i][2] = 0.f; acc[i][3] = 0.f; }

  for (int ch = 0; ch < 4; ++ch) {
    __syncthreads();  // A staged (first iter) / previous chunk consumed
#pragma unroll
    for (int it = 0; it < 4; ++it) {
      int f = it * 256 + tid;
      int r = f >> 5, c4 = f & 31;
      *(float4*)(&Wl[r][c4 * 4]) = *(const float4*)(W + (size_t)(ch * 32 + r) * FEAT + c4 * 4);
    }
    __syncthreads();
#pragma unroll
    for (int k4 = 0; k4 < 8; ++k4) {
      const int k = ch * 32 + k4 * 4;
      float a[4][4], w[4][4];
#pragma unroll
      for (int ri = 0; ri < 4; ++ri) {
        float4 av = *(const float4*)(&A[r0 + ri][k]);
        a[ri][0] = av.x; a[ri][1] = av.y; a[ri][2] = av.z; a[ri][3] = av.w;
      }
#pragma unroll
      for (int kk = 0; kk < 4; ++kk) {
        float4 wv = *(const float4*)(&Wl[k4 * 4 + kk][c0]);
        w[kk][0] = wv.x; w[kk][1] = wv.y; w[kk][2] = wv.z; w[kk][3] = wv.w;
      }
#pragma unroll
      for (int ri = 0; ri < 4; ++ri)
#pragma unroll
        for (int kk = 0; kk < 4; ++kk)
#pragma unroll
          for (int cj = 0; cj < 4; ++cj)
            acc[ri][cj] = fmaf(a[ri][kk], w[kk][cj], acc[ri][cj]);
    }
  }

  // fused el/er epilogue: per-thread partial over its 4 cols, shfl-reduce over 32 col-groups
  float4 al4 = *(const float4*)(al + c0);
  float4 ar4 = *(const float4*)(ar + c0);
  float pel[4], per_[4];
#pragma unroll
  for (int ri = 0; ri < 4; ++ri) {
    pel[ri]  = acc[ri][0] * al4.x + acc[ri][1] * al4.y + acc[ri][2] * al4.z + acc[ri][3] * al4.w;
    per_[ri] = acc[ri][0] * ar4.x + acc[ri][1] * ar4.y + acc[ri][2] * ar4.z + acc[ri][3] * ar4.w;
  }
#pragma unroll
  for (int mask = 16; mask > 0; mask >>= 1) {
#pragma unroll
    for (int ri = 0; ri < 4; ++ri) {
      pel[ri]  += __shfl_xor(pel[ri], mask);
      per_[ri] += __shfl_xor(per_[ri], mask);
    }
  }

#pragma unroll
  for (int ri = 0; ri < 4; ++ri) {
    int gr = row0 + r0 + ri;
    if (gr < N_NODES) {
      float4 o = make_float4(acc[ri][0], acc[ri][1], acc[ri][2], acc[ri][3]);
      *(float4*)(h + (size_t)gr * FEAT + c0) = o;
      if (cg == 0) { el[gr] = pel[ri]; er[gr] = per_[ri]; }
    }
  }
}

// ---------------- edge softmax + aggregate: one wave per destination node ----------------
// out[d] = (sum_e exp(e_e - m_d) * h[src_e]) / (sum_e exp(e_e - m_d)) + b
// (identical to normalizing alpha first). Empty segment -> out = b (matches JAX segment ops).

__global__ __launch_bounds__(256) void agg_kernel(
    const float* __restrict__ h, const float* __restrict__ el,
    const float* __restrict__ er, const int* __restrict__ offs,
    const int* __restrict__ ssrc, const float* __restrict__ bias,
    float* __restrict__ out)
{
  int wid = (blockIdx.x * 256 + threadIdx.x) >> 6;  // node id, one wave each
  int lane = threadIdx.x & 63;
  if (wid >= N_NODES) return;

  int beg = offs[wid], end = offs[wid + 1];
  float erd = er[wid];

  // pass 1: max over incoming edges (lane-strided)
  float m = -1e30f;
  for (int i = beg + lane; i < end; i += 64) {
    float e = el[ssrc[i]] + erd;
    e = e > 0.f ? e : NEG_SLOPE * e;
    m = fmaxf(m, e);
  }
#pragma unroll
  for (int mask = 32; mask > 0; mask >>= 1) m = fmaxf(m, __shfl_xor(m, mask));

  // pass 2: accumulate exp-weighted features; lanes split the 128 feats as float2
  float2 acc = make_float2(0.f, 0.f);
  float denom = 0.f;
  const float2* h2 = (const float2*)h;
  for (int i = beg; i < end; ++i) {
    int s = ssrc[i];                         // uniform across lanes -> broadcast
    float e = el[s] + erd;
    e = e > 0.f ? e : NEG_SLOPE * e;
    float ex = __expf(e - m);
    denom += ex;
    float2 v = h2[(size_t)s * 64 + lane];    // 512B coalesced gather per wave
    acc.x = fmaf(ex, v.x, acc.x);
    acc.y = fmaf(ex, v.y, acc.y);
  }

  float inv = denom > 0.f ? 1.f / denom : 0.f;   // deg==0 -> out = bias
  float2 bv = ((const float2*)bias)[lane];
  float2 o = make_float2(fmaf(acc.x, inv, bv.x), fmaf(acc.y, inv, bv.y));
  ((float2*)out)[(size_t)wid * 64 + lane] = o;
}

// ---------------- launch ----------------

extern "C" void kernel_launch(void* const* d_in, const int* in_sizes, int n_in,
                              void* d_out, int out_size, void* d_ws, size_t ws_size,
                              hipStream_t stream) {
  const float* x  = (const float*)d_in[0];
  const int* src  = (const int*)d_in[1];
  const int* dst  = (const int*)d_in[2];
  const float* W[3]  = {(const float*)d_in[3],  (const float*)d_in[7],  (const float*)d_in[11]};
  const float* al[3] = {(const float*)d_in[4],  (const float*)d_in[8],  (const float*)d_in[12]};
  const float* ar[3] = {(const float*)d_in[5],  (const float*)d_in[9],  (const float*)d_in[13]};
  const float* b[3]  = {(const float*)d_in[6],  (const float*)d_in[10], (const float*)d_in[14]};

  // workspace layout (~29 MB); d_out doubles as the inter-layer ping buffer
  float* hW  = (float*)d_ws;            // 6,400,000 f : transformed features of current layer
  float* el  = hW + 6400000;            // 50,016 f
  float* er  = el + 50016;              // 50,016 f
  int*   cnt = (int*)(er + 50016);      // 50,016 i : counts, then fill cursor
  int*   offs = cnt + 50016;            // 50,016 i : CSR offsets (N+1)
  int*   part = offs + 50016;           // 256 i
  int*   ssrc = part + 256;             // 625,000 i : edge sources sorted by dst

  // ---- CSR build (src/dst are fixed, but rebuild every call: no cross-call state) ----
  hipMemsetAsync(cnt, 0, N_NODES * sizeof(int), stream);
  hist_kernel<<<(N_EDGES + 255) / 256, 256, 0, stream>>>(dst, cnt);
  scan_part_kernel<<<NB_SCAN, 256, 0, stream>>>(cnt, part);
  scan_top_kernel<<<1, 256, 0, stream>>>(part, offs);
  scan_down_kernel<<<NB_SCAN, 256, 0, stream>>>(cnt, part, offs);
  fill_kernel<<<(N_EDGES + 255) / 256, 256, 0, stream>>>(src, dst, cnt, ssrc);

  const int gemm_grid = (N_NODES + BM - 1) / BM;   // 1563
  const int agg_grid  = (N_NODES + 3) / 4;         // 12500 (4 waves/block)
  float* outf = (float*)d_out;

  for (int l = 0; l < 3; ++l) {
    const float* lin = (l == 0) ? x : outf;        // relu applied on load for l>0
    gemm_kernel<<<gemm_grid, 256, 0, stream>>>(lin, W[l], al[l], ar[l], hW, el, er, l > 0 ? 1 : 0);
    agg_kernel<<<agg_grid, 256, 0, stream>>>(hW, el, er, offs, ssrc, b[l], outf);
  }
}

// Round 4
// 314.768 us; speedup vs baseline: 1.2781x; 1.2781x over previous
//
#include <hip/hip_runtime.h>

#define N_NODES 50000
#define N_EDGES 625000
#define FEAT 128
#define NEG_SLOPE 0.2f
#define BM 32
#define NB_SCAN 196   // ceil(50000/256)

// ---------------- CSR build ----------------

__global__ __launch_bounds__(256) void hist_kernel(const int* __restrict__ dst,
                                                   int* __restrict__ cnt) {
  int e = blockIdx.x * 256 + threadIdx.x;
  if (e < N_EDGES) atomicAdd(&cnt[dst[e]], 1);
}

__global__ __launch_bounds__(256) void scan_part_kernel(const int* __restrict__ cnt,
                                                        int* __restrict__ part) {
  __shared__ int s[256];
  int i = blockIdx.x * 256 + threadIdx.x;
  s[threadIdx.x] = (i < N_NODES) ? cnt[i] : 0;
  __syncthreads();
  for (int o = 128; o > 0; o >>= 1) {
    if (threadIdx.x < o) s[threadIdx.x] += s[threadIdx.x + o];
    __syncthreads();
  }
  if (threadIdx.x == 0) part[blockIdx.x] = s[0];
}

__global__ __launch_bounds__(256) void scan_top_kernel(int* __restrict__ part,
                                                       int* __restrict__ offs) {
  __shared__ int s[256];
  int tid = threadIdx.x;
  int v = (tid < NB_SCAN) ? part[tid] : 0;
  s[tid] = v;
  __syncthreads();
  for (int o = 1; o < 256; o <<= 1) {
    int t = (tid >= o) ? s[tid - o] : 0;
    __syncthreads();
    s[tid] += t;
    __syncthreads();
  }
  if (tid < NB_SCAN) part[tid] = s[tid] - v;  // exclusive scan of block sums
  if (tid == 255) offs[N_NODES] = s[255];     // total (= N_EDGES)
}

__global__ __launch_bounds__(256) void scan_down_kernel(int* __restrict__ cnt,
                                                        const int* __restrict__ part,
                                                        int* __restrict__ offs) {
  __shared__ int s[256];
  int tid = threadIdx.x;
  int i = blockIdx.x * 256 + tid;
  int v = (i < N_NODES) ? cnt[i] : 0;
  s[tid] = v;
  __syncthreads();
  for (int o = 1; o < 256; o <<= 1) {
    int t = (tid >= o) ? s[tid - o] : 0;
    __syncthreads();
    s[tid] += t;
    __syncthreads();
  }
  if (i < N_NODES) {
    int excl = s[tid] - v + part[blockIdx.x];
    offs[i] = excl;
    cnt[i] = excl;  // becomes the fill cursor
  }
}

__global__ __launch_bounds__(256) void fill_kernel(const int* __restrict__ src,
                                                   const int* __restrict__ dst,
                                                   int* __restrict__ cursor,
                                                   int* __restrict__ ssrc) {
  int e = blockIdx.x * 256 + threadIdx.x;
  if (e < N_EDGES) {
    int pos = atomicAdd(&cursor[dst[e]], 1);
    ssrc[pos] = src[e];
  }
}

// ---------------- GEMM: h = act(in) @ W, fused el = h@al, er = h@ar ----------------
// block: 256 threads = 8 row-groups x 32 col-groups; 4x4 outputs per thread.
// (unchanged this round — next target after agg)

__global__ __launch_bounds__(256) void gemm_kernel(
    const float* __restrict__ in, const float* __restrict__ W,
    const float* __restrict__ al, const float* __restrict__ ar,
    float* __restrict__ h, float* __restrict__ el, float* __restrict__ er,
    int applyRelu)
{
  __shared__ float A[BM][FEAT];    // 16 KB, full K staged once
  __shared__ float Wl[32][FEAT];   // 16 KB, K-chunked
  const int tid = threadIdx.x;
  const int row0 = blockIdx.x * BM;

#pragma unroll
  for (int it = 0; it < 4; ++it) {
    int f = it * 256 + tid;        // float4 id within 32x128 tile
    int r = f >> 5, c4 = f & 31;
    int gr = row0 + r;
    float4 v = make_float4(0.f, 0.f, 0.f, 0.f);
    if (gr < N_NODES) {
      v = *(const float4*)(in + (size_t)gr * FEAT + c4 * 4);
      if (applyRelu) {
        v.x = fmaxf(v.x, 0.f); v.y = fmaxf(v.y, 0.f);
        v.z = fmaxf(v.z, 0.f); v.w = fmaxf(v.w, 0.f);
      }
    }
    *(float4*)(&A[r][c4 * 4]) = v;
  }

  const int cg = tid & 31, rg = tid >> 5;
  const int c0 = cg * 4, r0 = rg * 4;
  float acc[4][4];
#pragma unroll
  for (int i = 0; i < 4; ++i) { acc[i][0] = 0.f; acc[i][1] = 0.f; acc[i][2] = 0.f; acc[i][3] = 0.f; }

  for (int ch = 0; ch < 4; ++ch) {
    __syncthreads();  // A staged (first iter) / previous chunk consumed
#pragma unroll
    for (int it = 0; it < 4; ++it) {
      int f = it * 256 + tid;
      int r = f >> 5, c4 = f & 31;
      *(float4*)(&Wl[r][c4 * 4]) = *(const float4*)(W + (size_t)(ch * 32 + r) * FEAT + c4 * 4);
    }
    __syncthreads();
#pragma unroll
    for (int k4 = 0; k4 < 8; ++k4) {
      const int k = ch * 32 + k4 * 4;
      float a[4][4], w[4][4];
#pragma unroll
      for (int ri = 0; ri < 4; ++ri) {
        float4 av = *(const float4*)(&A[r0 + ri][k]);
        a[ri][0] = av.x; a[ri][1] = av.y; a[ri][2] = av.z; a[ri][3] = av.w;
      }
#pragma unroll
      for (int kk = 0; kk < 4; ++kk) {
        float4 wv = *(const float4*)(&Wl[k4 * 4 + kk][c0]);
        w[kk][0] = wv.x; w[kk][1] = wv.y; w[kk][2] = wv.z; w[kk][3] = wv.w;
      }
#pragma unroll
      for (int ri = 0; ri < 4; ++ri)
#pragma unroll
        for (int kk = 0; kk < 4; ++kk)
#pragma unroll
          for (int cj = 0; cj < 4; ++cj)
            acc[ri][cj] = fmaf(a[ri][kk], w[kk][cj], acc[ri][cj]);
    }
  }

  float4 al4 = *(const float4*)(al + c0);
  float4 ar4 = *(const float4*)(ar + c0);
  float pel[4], per_[4];
#pragma unroll
  for (int ri = 0; ri < 4; ++ri) {
    pel[ri]  = acc[ri][0] * al4.x + acc[ri][1] * al4.y + acc[ri][2] * al4.z + acc[ri][3] * al4.w;
    per_[ri] = acc[ri][0] * ar4.x + acc[ri][1] * ar4.y + acc[ri][2] * ar4.z + acc[ri][3] * ar4.w;
  }
#pragma unroll
  for (int mask = 16; mask > 0; mask >>= 1) {
#pragma unroll
    for (int ri = 0; ri < 4; ++ri) {
      pel[ri]  += __shfl_xor(pel[ri], mask);
      per_[ri] += __shfl_xor(per_[ri], mask);
    }
  }

#pragma unroll
  for (int ri = 0; ri < 4; ++ri) {
    int gr = row0 + r0 + ri;
    if (gr < N_NODES) {
      float4 o = make_float4(acc[ri][0], acc[ri][1], acc[ri][2], acc[ri][3]);
      *(float4*)(h + (size_t)gr * FEAT + c0) = o;
      if (cg == 0) { el[gr] = pel[ri]; er[gr] = per_[ri]; }
    }
  }
}

// ---------------- edge softmax + aggregate: one wave per destination node ----------------
// Chunked register-cached form:
//   * ssrc/el read ONCE per edge (lane-strided), serving both max-reduce and exp
//   * running-max rescale handles deg > 64
//   * feature-gather loop: addresses from __shfl (VALU-only), 4x unrolled
//     -> 4 independent 512B gathers in flight per wave (was 1 dependent chain)
// out[d] = (sum_e exp(e_e - m_d) * h[src_e]) / denom + b  (== normalizing alpha first)

__global__ __launch_bounds__(256) void agg_kernel(
    const float* __restrict__ h, const float* __restrict__ el,
    const float* __restrict__ er, const int* __restrict__ offs,
    const int* __restrict__ ssrc, const float* __restrict__ bias,
    float* __restrict__ out)
{
  const int wid = (blockIdx.x * 256 + threadIdx.x) >> 6;  // node id, one wave each
  const int lane = threadIdx.x & 63;
  if (wid >= N_NODES) return;

  const int beg = offs[wid], end = offs[wid + 1];
  const float erd = er[wid];
  const float2* __restrict__ h2 = (const float2*)h;

  float2 acc = make_float2(0.f, 0.f);
  float denom = 0.f;
  float m = -1e30f;

  for (int base = beg; base < end; base += 64) {
    const int n = min(64, end - base);

    // load this chunk's edges once: src id + attention logit, lane-strided
    int s = 0;
    float e = -1e30f;
    if (lane < n) {
      s = ssrc[base + lane];
      float t = el[s] + erd;
      e = t > 0.f ? t : NEG_SLOPE * t;
    }

    // chunk max -> running max with rescale of prior accumulation
    float cm = e;
#pragma unroll
    for (int mask = 32; mask > 0; mask >>= 1) cm = fmaxf(cm, __shfl_xor(cm, mask));
    if (cm > m) {
      float scale = __expf(m - cm);   // first chunk: exp(-huge)=0, acc/denom already 0
      acc.x *= scale; acc.y *= scale; denom *= scale;
      m = cm;
    }

    float ex = (lane < n) ? __expf(e - m) : 0.f;
    float dsum = ex;
#pragma unroll
    for (int mask = 32; mask > 0; mask >>= 1) dsum += __shfl_xor(dsum, mask);
    denom += dsum;

    // feature gather: j uniform -> shfl broadcast; 4 loads in flight
    int j = 0;
    for (; j + 4 <= n; j += 4) {
      int   s0 = __shfl(s, j),      s1 = __shfl(s, j + 1);
      int   s2 = __shfl(s, j + 2),  s3 = __shfl(s, j + 3);
      float e0 = __shfl(ex, j),     e1 = __shfl(ex, j + 1);
      float e2 = __shfl(ex, j + 2), e3 = __shfl(ex, j + 3);
      float2 v0 = h2[(s0 << 6) + lane];
      float2 v1 = h2[(s1 << 6) + lane];
      float2 v2 = h2[(s2 << 6) + lane];
      float2 v3 = h2[(s3 << 6) + lane];
      acc.x = fmaf(e0, v0.x, acc.x); acc.y = fmaf(e0, v0.y, acc.y);
      acc.x = fmaf(e1, v1.x, acc.x); acc.y = fmaf(e1, v1.y, acc.y);
      acc.x = fmaf(e2, v2.x, acc.x); acc.y = fmaf(e2, v2.y, acc.y);
      acc.x = fmaf(e3, v3.x, acc.x); acc.y = fmaf(e3, v3.y, acc.y);
    }
    for (; j < n; ++j) {
      int   sj = __shfl(s, j);
      float ej = __shfl(ex, j);
      float2 v = h2[(sj << 6) + lane];
      acc.x = fmaf(ej, v.x, acc.x); acc.y = fmaf(ej, v.y, acc.y);
    }
  }

  float inv = denom > 0.f ? 1.f / denom : 0.f;   // deg==0 -> out = bias
  float2 bv = ((const float2*)bias)[lane];
  float2 o = make_float2(fmaf(acc.x, inv, bv.x), fmaf(acc.y, inv, bv.y));
  ((float2*)out)[(wid << 6) + lane] = o;
}

// ---------------- launch ----------------

extern "C" void kernel_launch(void* const* d_in, const int* in_sizes, int n_in,
                              void* d_out, int out_size, void* d_ws, size_t ws_size,
                              hipStream_t stream) {
  const float* x  = (const float*)d_in[0];
  const int* src  = (const int*)d_in[1];
  const int* dst  = (const int*)d_in[2];
  const float* W[3]  = {(const float*)d_in[3],  (const float*)d_in[7],  (const float*)d_in[11]};
  const float* al[3] = {(const float*)d_in[4],  (const float*)d_in[8],  (const float*)d_in[12]};
  const float* ar[3] = {(const float*)d_in[5],  (const float*)d_in[9],  (const float*)d_in[13]};
  const float* b[3]  = {(const float*)d_in[6],  (const float*)d_in[10], (const float*)d_in[14]};

  // workspace layout (~29 MB); d_out doubles as the inter-layer ping buffer
  float* hW  = (float*)d_ws;            // 6,400,000 f : transformed features of current layer
  float* el  = hW + 6400000;            // 50,016 f
  float* er  = el + 50016;              // 50,016 f
  int*   cnt = (int*)(er + 50016);      // 50,016 i : counts, then fill cursor
  int*   offs = cnt + 50016;            // 50,016 i : CSR offsets (N+1)
  int*   part = offs + 50016;           // 256 i
  int*   ssrc = part + 256;             // 625,000 i : edge sources sorted by dst

  // ---- CSR build (rebuild every call: no cross-call state) ----
  hipMemsetAsync(cnt, 0, N_NODES * sizeof(int), stream);
  hist_kernel<<<(N_EDGES + 255) / 256, 256, 0, stream>>>(dst, cnt);
  scan_part_kernel<<<NB_SCAN, 256, 0, stream>>>(cnt, part);
  scan_top_kernel<<<1, 256, 0, stream>>>(part, offs);
  scan_down_kernel<<<NB_SCAN, 256, 0, stream>>>(cnt, part, offs);
  fill_kernel<<<(N_EDGES + 255) / 256, 256, 0, stream>>>(src, dst, cnt, ssrc);

  const int gemm_grid = (N_NODES + BM - 1) / BM;   // 1563
  const int agg_grid  = (N_NODES + 3) / 4;         // 12500 (4 waves/block)
  float* outf = (float*)d_out;

  for (int l = 0; l < 3; ++l) {
    const float* lin = (l == 0) ? x : outf;        // relu applied on load for l>0
    gemm_kernel<<<gemm_grid, 256, 0, stream>>>(lin, W[l], al[l], ar[l], hW, el, er, l > 0 ? 1 : 0);
    agg_kernel<<<agg_grid, 256, 0, stream>>>(hW, el, er, offs, ssrc, b[l], outf);
  }
}